// Round 1
// baseline (9328.058 us; speedup 1.0000x reference)
//
#include <hip/hip_runtime.h>
#include <math.h>

// ---------------------------------------------------------------------------
// VQSign: 3D conv encoder (3 stages, per-clip BN) -> proj -> VQ -> GRU+losses
// All fp32. Layout notes:
//   P-buffers: zero-padded conv inputs [N][C][18][H+2][WP], WP = W+2 rounded
//   up to a multiple of 4 floats so rows are 16B aligned (float4 loads).
//   Conv blocks are single output-channel so BN stats reduce in-epilogue.
// ---------------------------------------------------------------------------

// ---------------- pad clip: x[4,3,64,96,96] slice -> P1 [4,3,18,98,100] -----
__global__ void pad_clip_k(const float* __restrict__ x, float* __restrict__ p1, int t0) {
    const int WP = 100, HPAD = 98, TP = 18;
    int idx = blockIdx.x * 256 + threadIdx.x;
    const int total = 4 * 3 * TP * HPAD * WP;   // 2,116,800
    if (idx >= total) return;
    int xp = idx % WP; int r = idx / WP;
    int yp = r % HPAD; r /= HPAD;
    int tp = r % TP;   r /= TP;
    int c = r % 3; int n = r / 3;
    float v = 0.f;
    if (tp >= 1 && tp <= 16 && yp >= 1 && yp <= 96 && xp >= 1 && xp <= 96) {
        v = x[(((size_t)(n * 3 + c) * 64 + (t0 + tp - 1)) * 96 + (yp - 1)) * 96 + (xp - 1)];
    }
    p1[idx] = v;
}

// ---------------- generic 3x3x3 conv, pad=1 (input pre-padded) --------------
// in : [4][CIN][18][H+2][WP]   out: [4][COUT][16][H][W]
// block = (n, co, t-block); each thread computes a 4x4 (y,x) output tile.
// Epilogue: block-reduce sum/sumsq -> atomicAdd into stats[co*2 + {0,1}].
template<int CIN, int COUT, int H, int W, int WP, int TB, int NTH>
__launch_bounds__(NTH)
__global__ void convk(const float* __restrict__ in, const float* __restrict__ wgt,
                      const float* __restrict__ bias, float* __restrict__ out,
                      float* __restrict__ stats) {
    constexpr int HP = H + 2;
    constexpr int TBLKS = 16 / TB;
    constexpr int GX = W / 4, GY = H / 4;
    constexpr int NG = TB * GY * GX;
    int bb = blockIdx.x;
    int tb = bb % TBLKS; bb /= TBLKS;
    int co = bb % COUT;  int n = bb / COUT;

    __shared__ float ws[CIN * 27];
    __shared__ float red[8];
    for (int i = threadIdx.x; i < CIN * 27; i += NTH) ws[i] = wgt[(size_t)co * CIN * 27 + i];
    float bv = bias[co];
    __syncthreads();

    const float* inb = in + (size_t)n * CIN * 18 * HP * WP;
    float lsum = 0.f, lsq = 0.f;

    for (int g = threadIdx.x; g < NG; g += NTH) {
        int xg = (g % GX) * 4;
        int yg = ((g / GX) % GY) * 4;
        int t  = tb * TB + g / (GX * GY);
        float acc[4][4];
        #pragma unroll
        for (int i = 0; i < 4; ++i) { acc[i][0] = bv; acc[i][1] = bv; acc[i][2] = bv; acc[i][3] = bv; }
        const float* wp = ws;
        for (int ci = 0; ci < CIN; ++ci) {
            const float* ip = inb + ((size_t)ci * 18 + t) * (HP * WP) + (size_t)yg * WP + xg;
            #pragma unroll
            for (int kt = 0; kt < 3; ++kt) {
                float w_[9];
                #pragma unroll
                for (int i = 0; i < 9; ++i) w_[i] = wp[kt * 9 + i];
                #pragma unroll
                for (int j = 0; j < 6; ++j) {
                    const float* rp = ip + (kt * HP + j) * WP;
                    float4 v4 = *(const float4*)rp;
                    float v4a = rp[4], v5 = rp[5];
                    #pragma unroll
                    for (int ky = 0; ky < 3; ++ky) {
                        int i = j - ky;
                        if (i >= 0 && i < 4) {
                            float w0 = w_[ky * 3], w1 = w_[ky * 3 + 1], w2 = w_[ky * 3 + 2];
                            acc[i][0] += w0 * v4.x + w1 * v4.y + w2 * v4.z;
                            acc[i][1] += w0 * v4.y + w1 * v4.z + w2 * v4.w;
                            acc[i][2] += w0 * v4.z + w1 * v4.w + w2 * v4a;
                            acc[i][3] += w0 * v4.w + w1 * v4a + w2 * v5;
                        }
                    }
                }
            }
            wp += 27;
        }
        #pragma unroll
        for (int i = 0; i < 4; ++i) {
            size_t oidx = ((((size_t)n * COUT + co) * 16 + t) * H + (yg + i)) * W + xg;
            *(float4*)(out + oidx) = make_float4(acc[i][0], acc[i][1], acc[i][2], acc[i][3]);
            #pragma unroll
            for (int xx = 0; xx < 4; ++xx) { lsum += acc[i][xx]; lsq += acc[i][xx] * acc[i][xx]; }
        }
    }
    // block reduce (NTH/64 waves)
    #pragma unroll
    for (int o = 32; o > 0; o >>= 1) { lsum += __shfl_down(lsum, o, 64); lsq += __shfl_down(lsq, o, 64); }
    constexpr int NW = NTH / 64;
    int lane = threadIdx.x & 63, wv = threadIdx.x >> 6;
    if (lane == 0) { red[wv] = lsum; red[NW + wv] = lsq; }
    __syncthreads();
    if (threadIdx.x == 0) {
        float s = 0.f, s2 = 0.f;
        for (int i = 0; i < NW; ++i) { s += red[i]; s2 += red[NW + i]; }
        atomicAdd(&stats[co * 2], s);
        atomicAdd(&stats[co * 2 + 1], s2);
    }
}

// -------- BN(+stats) + ReLU + 2x2 maxpool, writes padded next-stage input ---
// cin: [4][C][16][H][W] -> outp: [4][C][18][HO+2][WP] (zeros in pad)
template<int C, int H, int W, int HO, int WO, int WP>
__global__ void bnpoolk(const float* __restrict__ cin, const float* __restrict__ stats,
                        const float* __restrict__ gam, const float* __restrict__ bet,
                        float* __restrict__ outp, float inv_n) {
    constexpr int HOP = HO + 2;
    int idx = blockIdx.x * 256 + threadIdx.x;
    const int total = 4 * C * 18 * HOP * WP;
    if (idx >= total) return;
    int xp = idx % WP; int r = idx / WP;
    int yp = r % HOP; r /= HOP;
    int tp = r % 18;  r /= 18;
    int c = r % C; int n = r / C;
    float v = 0.f;
    if (tp >= 1 && tp <= 16 && yp >= 1 && yp <= HO && xp >= 1 && xp <= WO) {
        float mean = stats[c * 2] * inv_n;
        float var  = stats[c * 2 + 1] * inv_n - mean * mean;
        var = var < 0.f ? 0.f : var;
        float sc = gam[c] / sqrtf(var + 1e-5f);
        float sh = bet[c] - mean * sc;
        const float* bp = cin + ((((size_t)n * C + c) * 16 + (tp - 1)) * H + 2 * (yp - 1)) * W + 2 * (xp - 1);
        float a = bp[0] * sc + sh, b = bp[1] * sc + sh;
        float c2 = bp[W] * sc + sh, d = bp[W + 1] * sc + sh;
        v = fmaxf(fmaxf(fmaxf(a, b), fmaxf(c2, d)), 0.f);
    }
    outp[idx] = v;
}

// -------- BN + ReLU + adaptive avgpool 6x6 -> enc[n][c*256 + t*16 + y*4 + x] -
__global__ void bnavgk(const float* __restrict__ c3, const float* __restrict__ stats,
                       const float* __restrict__ gam, const float* __restrict__ bet,
                       float* __restrict__ enc, float inv_n) {
    int idx = blockIdx.x * 256 + threadIdx.x;   // 131072 exact
    int x = idx & 3, y = (idx >> 2) & 3, t = (idx >> 4) & 15, c = (idx >> 8) & 127, n = idx >> 15;
    float mean = stats[c * 2] * inv_n;
    float var  = stats[c * 2 + 1] * inv_n - mean * mean;
    var = var < 0.f ? 0.f : var;
    float sc = gam[c] / sqrtf(var + 1e-5f);
    float sh = bet[c] - mean * sc;
    const float* base = c3 + ((((size_t)n * 128 + c) * 16 + t) * 24 + y * 6) * 24 + x * 6;
    float s = 0.f;
    #pragma unroll
    for (int wy = 0; wy < 6; ++wy)
        #pragma unroll
        for (int wx = 0; wx < 6; ++wx)
            s += fmaxf(base[wy * 24 + wx] * sc + sh, 0.f);
    enc[(size_t)n * 32768 + (size_t)c * 256 + t * 16 + y * 4 + x] = s * (1.f / 36.f);
}

// -------- proj: feat[n*7+l][d] = enc[l][n] . proj_w[d] + pb[d] --------------
__global__ void projk(const float* __restrict__ enc, const float* __restrict__ pw,
                      const float* __restrict__ pb, float* __restrict__ feat) {
    int d = blockIdx.x;                  // 256 blocks
    float acc[28];
    #pragma unroll
    for (int e = 0; e < 28; ++e) acc[e] = 0.f;
    const float* wrow = pw + (size_t)d * 32768;
    for (int k = threadIdx.x; k < 32768; k += 256) {
        float wv = wrow[k];
        #pragma unroll
        for (int e = 0; e < 28; ++e) acc[e] += enc[(size_t)e * 32768 + k] * wv;
    }
    __shared__ float red[4 * 28];
    #pragma unroll
    for (int e = 0; e < 28; ++e) {
        float v = acc[e];
        #pragma unroll
        for (int o = 32; o > 0; o >>= 1) v += __shfl_down(v, o, 64);
        if ((threadIdx.x & 63) == 0) red[(threadIdx.x >> 6) * 28 + e] = v;
    }
    __syncthreads();
    if (threadIdx.x < 28) {
        int e = threadIdx.x;               // e = l*4 + n
        int l = e >> 2, n = e & 3;
        float s = red[e] + red[28 + e] + red[56 + e] + red[84 + e] + pb[d];
        feat[(size_t)(n * 7 + l) * 256 + d] = s;
    }
}

// -------- VQ: argmin_k (|c_k|^2 - 2 f.c_k), fp64 accum, packed atomicMin ----
__global__ void quantk(const float* __restrict__ feat, const float* __restrict__ cb,
                       unsigned long long* __restrict__ best) {
    __shared__ float fs[28 * 256];
    for (int i = threadIdx.x; i < 7168; i += 256) fs[i] = feat[i];
    __syncthreads();
    int k = blockIdx.x * 256 + threadIdx.x;    // 8192 codes
    const float* crow = cb + (size_t)k * 256;
    double dot[28];
    #pragma unroll
    for (int r = 0; r < 28; ++r) dot[r] = 0.0;
    double cn = 0.0;
    for (int d = 0; d < 256; ++d) {
        double c = (double)crow[d];
        cn += c * c;
        #pragma unroll
        for (int r = 0; r < 28; ++r) dot[r] += (double)fs[r * 256 + d] * c;
    }
    #pragma unroll
    for (int r = 0; r < 28; ++r) {
        float s = (float)(cn - 2.0 * dot[r]);
        unsigned int bits = __float_as_uint(s);
        unsigned int key = (bits & 0x80000000u) ? ~bits : (bits | 0x80000000u);
        unsigned long long p = ((unsigned long long)key << 32) | (unsigned int)k;
        #pragma unroll
        for (int o = 32; o > 0; o >>= 1) {
            unsigned long long q = __shfl_down(p, o, 64);
            if (q < p) p = q;
        }
        if ((threadIdx.x & 63) == 0) atomicMin(&best[r], p);
    }
}

// -------- gather codebook rows, write tokens+quantized, commitment SSE ------
__global__ void gatherk(const unsigned long long* __restrict__ best,
                        const float* __restrict__ feat, const float* __restrict__ cb,
                        float* __restrict__ dout, float* __restrict__ quant,
                        float* __restrict__ acc) {
    int r = blockIdx.x;        // 28
    int d = threadIdx.x;       // 256
    int idx = (int)(best[r] & 0xFFFFFFFFull);
    float q = cb[(size_t)idx * 256 + d];
    quant[r * 256 + d] = q;
    dout[28 + r * 256 + d] = q;
    if (d == 0) dout[r] = (float)idx;
    float df = feat[r * 256 + d] - q;
    float v = df * df;
    #pragma unroll
    for (int o = 32; o > 0; o >>= 1) v += __shfl_down(v, o, 64);
    if ((d & 63) == 0) atomicAdd(&acc[0], v);
}

// -------- gx = quant[:, :6] @ w_ih.T + b_ih --------------------------------
__global__ void gxk(const float* __restrict__ quant, const float* __restrict__ wih,
                    const float* __restrict__ bih, float* __restrict__ gx) {
    int o = blockIdx.x * 256 + threadIdx.x;   // 4*6*768 = 18432
    int g = o % 768; int t = (o / 768) % 6; int n = o / (768 * 6);
    const float* q = quant + (size_t)(n * 7 + t) * 256;
    const float* w = wih + (size_t)g * 256;
    float s = bih[g];
    #pragma unroll 4
    for (int d = 0; d < 256; ++d) s += q[d] * w[d];
    gx[o] = s;
}

// -------- one GRU step + context SSE ---------------------------------------
__global__ void gruk(const float* __restrict__ gx, const float* __restrict__ whh,
                     const float* __restrict__ bhh, float* __restrict__ h,
                     const float* __restrict__ feat, float* __restrict__ acc, int t) {
    int b = blockIdx.x;        // 4
    int d = threadIdx.x;       // 256
    __shared__ float hs[256];
    hs[d] = h[b * 256 + d];
    __syncthreads();
    float g0 = bhh[d], g1 = bhh[256 + d], g2 = bhh[512 + d];
    const float* w0 = whh + (size_t)d * 256;
    const float* w1 = whh + (size_t)(256 + d) * 256;
    const float* w2 = whh + (size_t)(512 + d) * 256;
    #pragma unroll 4
    for (int k = 0; k < 256; ++k) {
        float hv = hs[k];
        g0 += w0[k] * hv; g1 += w1[k] * hv; g2 += w2[k] * hv;
    }
    const float* gxr = gx + (size_t)(b * 6 + t) * 768;
    float xr = gxr[d], xz = gxr[256 + d], xn = gxr[512 + d];
    float rr = 1.f / (1.f + expf(-(xr + g0)));
    float zz = 1.f / (1.f + expf(-(xz + g1)));
    float nn = tanhf(xn + rr * g2);
    float h2 = (1.f - zz) * nn + zz * hs[d];
    h[b * 256 + d] = h2;
    float df = h2 - feat[(size_t)(b * 7 + t + 1) * 256 + d];
    float v = df * df;
    #pragma unroll
    for (int o = 32; o > 0; o >>= 1) v += __shfl_down(v, o, 64);
    if ((d & 63) == 0) atomicAdd(&acc[1], v);
}

// -------- finalize losses ---------------------------------------------------
__global__ void fink(const float* __restrict__ acc, float* __restrict__ dout) {
    float comm = acc[0] / 7168.f;
    float ctx  = acc[1] / 6144.f;
    dout[7196] = comm;
    dout[7197] = comm;          // codebook loss == commitment loss numerically
    dout[7198] = ctx;
    dout[7199] = comm + 0.25f * comm + 0.1f * ctx;
}

// ---------------------------------------------------------------------------
extern "C" void kernel_launch(void* const* d_in, const int* in_sizes, int n_in,
                              void* d_out, int out_size, void* d_ws, size_t ws_size,
                              hipStream_t stream) {
    (void)in_sizes; (void)n_in; (void)out_size; (void)ws_size;
    const float* x    = (const float*)d_in[0];
    const float* c1w  = (const float*)d_in[1];
    const float* c1b  = (const float*)d_in[2];
    const float* bn1g = (const float*)d_in[3];
    const float* bn1b = (const float*)d_in[4];
    const float* c2w  = (const float*)d_in[5];
    const float* c2b  = (const float*)d_in[6];
    const float* bn2g = (const float*)d_in[7];
    const float* bn2b = (const float*)d_in[8];
    const float* c3w  = (const float*)d_in[9];
    const float* c3b  = (const float*)d_in[10];
    const float* bn3g = (const float*)d_in[11];
    const float* bn3b = (const float*)d_in[12];
    const float* pw   = (const float*)d_in[13];
    const float* pb   = (const float*)d_in[14];
    const float* cb   = (const float*)d_in[15];
    const float* wih  = (const float*)d_in[16];
    const float* whh  = (const float*)d_in[17];
    const float* bih  = (const float*)d_in[18];
    const float* bhh  = (const float*)d_in[19];
    float* out = (float*)d_out;

    // workspace layout (floats). A/B ping-pong: A holds conv outputs (C1/C2/C3),
    // B holds padded conv inputs (P1/P2/P3). Total ~103 MB.
    float* ws    = (float*)d_ws;
    float* A     = ws;                      // 18,874,368 (C1; reused for C2, C3)
    float* B     = A + 18874368;            //  5,990,400 (P1 2.1M / P2 6.0M / P3 3.4M)
    float* enc   = B + 5990400;             //    917,504 = 7*4*32768
    float* feat  = enc + 917504;            //      7,168
    float* quant = feat + 7168;             //      7,168
    float* gx    = quant + 7168;            //     18,432
    float* h     = gx + 18432;              //      1,024
    float* stats = h + 1024;                //        256
    float* acc   = stats + 256;             //          4
    unsigned long long* best = (unsigned long long*)(acc + 4); // 28 u64

    for (int l = 0; l < 7; ++l) {
        pad_clip_k<<<8269, 256, 0, stream>>>(x, B, l * 8);
        hipMemsetAsync(stats, 0, 256 * sizeof(float), stream);
        convk<3, 32, 96, 96, 100, 1, 256><<<2048, 256, 0, stream>>>(B, c1w, c1b, A, stats);
        bnpoolk<32, 96, 96, 48, 48, 52><<<23400, 256, 0, stream>>>(A, stats, bn1g, bn1b, B, 1.0f / 589824.0f);
        hipMemsetAsync(stats, 0, 256 * sizeof(float), stream);
        convk<32, 64, 48, 48, 52, 1, 128><<<4096, 128, 0, stream>>>(B, c2w, c2b, A, stats);
        bnpoolk<64, 48, 48, 24, 24, 28><<<13104, 256, 0, stream>>>(A, stats, bn2g, bn2b, B, 1.0f / 147456.0f);
        hipMemsetAsync(stats, 0, 256 * sizeof(float), stream);
        convk<64, 128, 24, 24, 28, 16, 256><<<512, 256, 0, stream>>>(B, c3w, c3b, A, stats);
        bnavgk<<<512, 256, 0, stream>>>(A, stats, bn3g, bn3b, enc + (size_t)l * 131072, 1.0f / 36864.0f);
    }

    projk<<<256, 256, 0, stream>>>(enc, pw, pb, feat);
    hipMemsetAsync(best, 0xFF, 28 * sizeof(unsigned long long), stream);
    hipMemsetAsync(acc, 0, 4 * sizeof(float), stream);
    hipMemsetAsync(h, 0, 1024 * sizeof(float), stream);
    quantk<<<32, 256, 0, stream>>>(feat, cb, best);
    gatherk<<<28, 256, 0, stream>>>(best, feat, cb, out, quant, acc);
    gxk<<<72, 256, 0, stream>>>(quant, wih, bih, gx);
    for (int t = 0; t < 6; ++t)
        gruk<<<4, 256, 0, stream>>>(gx, whh, bhh, h, feat, acc, t);
    fink<<<1, 1, 0, stream>>>(acc, out);
}

// Round 2
// 3893.416 us; speedup vs baseline: 2.3959x; 2.3959x over previous
//
#include <hip/hip_runtime.h>
#include <math.h>

// ---------------------------------------------------------------------------
// VQSign r2: conv2/conv3 -> split-bf16 MFMA implicit GEMM (27-offset shifted
// GEMM, channels-last hi/lo padded inputs, weights LDS-staged per kt/ky).
// conv1 stays fp32 VALU (3 input channels, 9% of FLOPs). VQ argmin exact.
// ---------------------------------------------------------------------------

typedef __attribute__((ext_vector_type(8))) short short8;
typedef __attribute__((ext_vector_type(4))) float f32x4;

__device__ inline unsigned short f2bf(float x) {
    unsigned int u = __float_as_uint(x);
    u += 0x7FFFu + ((u >> 16) & 1u);          // RNE
    return (unsigned short)(u >> 16);
}
__device__ inline float bf2f(unsigned short h) {
    return __uint_as_float(((unsigned int)h) << 16);
}

// ---------------- pad clip: x[4,3,64,96,96] slice -> P1 [4,3,18,98,100] -----
__global__ void pad_clip_k(const float* __restrict__ x, float* __restrict__ p1, int t0) {
    const int WP = 100, HPAD = 98, TP = 18;
    int idx = blockIdx.x * 256 + threadIdx.x;
    const int total = 4 * 3 * TP * HPAD * WP;
    if (idx >= total) return;
    int xp = idx % WP; int r = idx / WP;
    int yp = r % HPAD; r /= HPAD;
    int tp = r % TP;   r /= TP;
    int c = r % 3; int n = r / 3;
    float v = 0.f;
    if (tp >= 1 && tp <= 16 && yp >= 1 && yp <= 96 && xp >= 1 && xp <= 96) {
        v = x[(((size_t)(n * 3 + c) * 64 + (t0 + tp - 1)) * 96 + (yp - 1)) * 96 + (xp - 1)];
    }
    p1[idx] = v;
}

// ---------------- conv1: fp32 3x3x3, stats fused (unchanged from r1) --------
template<int CIN, int COUT, int H, int W, int WP, int TB, int NTH>
__launch_bounds__(NTH)
__global__ void convk(const float* __restrict__ in, const float* __restrict__ wgt,
                      const float* __restrict__ bias, float* __restrict__ out,
                      float* __restrict__ stats) {
    constexpr int HP = H + 2;
    constexpr int TBLKS = 16 / TB;
    constexpr int GX = W / 4, GY = H / 4;
    constexpr int NG = TB * GY * GX;
    int bb = blockIdx.x;
    int tb = bb % TBLKS; bb /= TBLKS;
    int co = bb % COUT;  int n = bb / COUT;

    __shared__ float ws[CIN * 27];
    __shared__ float red[8];
    for (int i = threadIdx.x; i < CIN * 27; i += NTH) ws[i] = wgt[(size_t)co * CIN * 27 + i];
    float bv = bias[co];
    __syncthreads();

    const float* inb = in + (size_t)n * CIN * 18 * HP * WP;
    float lsum = 0.f, lsq = 0.f;

    for (int g = threadIdx.x; g < NG; g += NTH) {
        int xg = (g % GX) * 4;
        int yg = ((g / GX) % GY) * 4;
        int t  = tb * TB + g / (GX * GY);
        float acc[4][4];
        #pragma unroll
        for (int i = 0; i < 4; ++i) { acc[i][0] = bv; acc[i][1] = bv; acc[i][2] = bv; acc[i][3] = bv; }
        const float* wp = ws;
        for (int ci = 0; ci < CIN; ++ci) {
            const float* ip = inb + ((size_t)ci * 18 + t) * (HP * WP) + (size_t)yg * WP + xg;
            #pragma unroll
            for (int kt = 0; kt < 3; ++kt) {
                float w_[9];
                #pragma unroll
                for (int i = 0; i < 9; ++i) w_[i] = wp[kt * 9 + i];
                #pragma unroll
                for (int j = 0; j < 6; ++j) {
                    const float* rp = ip + (kt * HP + j) * WP;
                    float4 v4 = *(const float4*)rp;
                    float v4a = rp[4], v5 = rp[5];
                    #pragma unroll
                    for (int ky = 0; ky < 3; ++ky) {
                        int i = j - ky;
                        if (i >= 0 && i < 4) {
                            float w0 = w_[ky * 3], w1 = w_[ky * 3 + 1], w2 = w_[ky * 3 + 2];
                            acc[i][0] += w0 * v4.x + w1 * v4.y + w2 * v4.z;
                            acc[i][1] += w0 * v4.y + w1 * v4.z + w2 * v4.w;
                            acc[i][2] += w0 * v4.z + w1 * v4.w + w2 * v4a;
                            acc[i][3] += w0 * v4.w + w1 * v4a + w2 * v5;
                        }
                    }
                }
            }
            wp += 27;
        }
        #pragma unroll
        for (int i = 0; i < 4; ++i) {
            size_t oidx = ((((size_t)n * COUT + co) * 16 + t) * H + (yg + i)) * W + xg;
            *(float4*)(out + oidx) = make_float4(acc[i][0], acc[i][1], acc[i][2], acc[i][3]);
            #pragma unroll
            for (int xx = 0; xx < 4; ++xx) { lsum += acc[i][xx]; lsq += acc[i][xx] * acc[i][xx]; }
        }
    }
    #pragma unroll
    for (int o = 32; o > 0; o >>= 1) { lsum += __shfl_down(lsum, o, 64); lsq += __shfl_down(lsq, o, 64); }
    constexpr int NW = NTH / 64;
    int lane = threadIdx.x & 63, wv = threadIdx.x >> 6;
    if (lane == 0) { red[wv] = lsum; red[NW + wv] = lsq; }
    __syncthreads();
    if (threadIdx.x == 0) {
        float s = 0.f, s2 = 0.f;
        for (int i = 0; i < NW; ++i) { s += red[i]; s2 += red[NW + i]; }
        atomicAdd(&stats[co * 2], s);
        atomicAdd(&stats[co * 2 + 1], s2);
    }
}

// -------- bnpool1: conv1 out (chan-first fp32) -> P2 hi/lo chan-last --------
// P2: [n][18][50][52][32] bf16 (pads pre-zeroed by memset). One block per
// output row (n,t,yo). LDS transpose: [48 x][33] packed (lo<<16|hi) words.
__global__ void bnpool1k(const float* __restrict__ cin, const float* __restrict__ st,
                         const float* __restrict__ gam, const float* __restrict__ bet,
                         unsigned short* __restrict__ phi, unsigned short* __restrict__ plo) {
    int b = blockIdx.x;                // 3072 = 4n * 16t * 48yo
    int yo = b % 48; int t = (b / 48) % 16; int n = b / 768;
    __shared__ unsigned int arr[48 * 33];
    int tid = threadIdx.x;
    int c = tid >> 3, k = tid & 7;     // c: channel 0..31, k: x-chunk 0..7
    float mean = st[c * 2] * (1.f / 589824.f);
    float var  = st[c * 2 + 1] * (1.f / 589824.f) - mean * mean;
    var = var < 0.f ? 0.f : var;
    float sc = gam[c] / sqrtf(var + 1e-5f);
    float sh = bet[c] - mean * sc;

    const float* base = cin + (((size_t)(n * 32 + c) * 16 + t) * 96 + 2 * yo) * 96 + k * 12;
    float r0[12], r1[12];
    *(float4*)(r0 + 0) = *(const float4*)(base + 0);
    *(float4*)(r0 + 4) = *(const float4*)(base + 4);
    *(float4*)(r0 + 8) = *(const float4*)(base + 8);
    *(float4*)(r1 + 0) = *(const float4*)(base + 96);
    *(float4*)(r1 + 4) = *(const float4*)(base + 100);
    *(float4*)(r1 + 8) = *(const float4*)(base + 104);
    #pragma unroll
    for (int j = 0; j < 6; ++j) {
        float a  = r0[2 * j] * sc + sh, bb = r0[2 * j + 1] * sc + sh;
        float c2 = r1[2 * j] * sc + sh, d  = r1[2 * j + 1] * sc + sh;
        float v = fmaxf(fmaxf(fmaxf(a, bb), fmaxf(c2, d)), 0.f);
        unsigned short hi = f2bf(v);
        unsigned short lo = f2bf(v - bf2f(hi));
        arr[(k * 6 + j) * 33 + c] = (unsigned int)hi | ((unsigned int)lo << 16);
    }
    __syncthreads();
    if (tid < 192) {
        int xp = 1 + (tid >> 2); int cq = tid & 3;
        union { unsigned short s[8]; uint4 v; } Uh, Ul;
        #pragma unroll
        for (int i = 0; i < 8; ++i) {
            unsigned int w = arr[(xp - 1) * 33 + cq * 8 + i];
            Uh.s[i] = (unsigned short)(w & 0xFFFFu);
            Ul.s[i] = (unsigned short)(w >> 16);
        }
        size_t off = ((((size_t)n * 18 + t + 1) * 50 + yo + 1) * 52 + xp) * 32 + cq * 8;
        *(uint4*)(phi + off) = Uh.v;
        *(uint4*)(plo + off) = Ul.v;
    }
}

// -------- conv2: split-bf16 MFMA. in P2 [n][18][50][52][32] hi/lo ----------
// out: [n][16][48][48][64] fp32 chan-last. W2P: [3kt][9o][2h][64co][32ci] bf16.
// Block: 256 thr / 4 waves, one (n,t,4-row strip); wave = 1 y-row, M=64,N=48.
__launch_bounds__(256, 2)
__global__ void conv2k(const unsigned short* __restrict__ phi, const unsigned short* __restrict__ plo,
                       const unsigned short* __restrict__ w2p, const float* __restrict__ bias,
                       float* __restrict__ out) {
    __shared__ unsigned short lds[36864];      // 72 KiB: one kt-slab of weights
    int b = blockIdx.x;                        // 768 = 4n*16t*12 strips
    int y0 = (b % 12) * 4; int t = (b / 12) % 16; int n = b / 192;
    int wv = threadIdx.x >> 6, lane = threadIdx.x & 63;
    int c = lane & 15, q = lane >> 4;
    int y = y0 + wv;

    f32x4 acc[4][3];
    #pragma unroll
    for (int i = 0; i < 4; ++i)
        #pragma unroll
        for (int j = 0; j < 3; ++j) acc[i][j] = (f32x4)0.f;

    const int laneoff = c * 32 + q * 8;
    for (int kt = 0; kt < 3; ++kt) {
        const uint4* src = (const uint4*)(w2p + kt * 36864);
        uint4* dst = (uint4*)lds;
        __syncthreads();
        for (int i = threadIdx.x; i < 4608; i += 256) dst[i] = src[i];
        __syncthreads();
        const unsigned short* ph_t = phi + ((size_t)(n * 18 + t + kt) * 50) * (52 * 32);
        const unsigned short* pl_t = plo + ((size_t)(n * 18 + t + kt) * 50) * (52 * 32);
        #pragma unroll
        for (int ky = 0; ky < 3; ++ky) {
            const unsigned short* rowh = ph_t + (y + ky) * (52 * 32) + laneoff;
            const unsigned short* rowl = pl_t + (y + ky) * (52 * 32) + laneoff;
            #pragma unroll
            for (int kx = 0; kx < 3; ++kx) {
                int o = ky * 3 + kx;
                const unsigned short* wb = lds + o * 4096 + laneoff;   // m==c, same lane offset
                short8 ah[4], al[4], bh[3], bl[3];
                #pragma unroll
                for (int mb = 0; mb < 4; ++mb) {
                    ah[mb] = *(const short8*)(wb + mb * 512);
                    al[mb] = *(const short8*)(wb + 2048 + mb * 512);
                }
                #pragma unroll
                for (int xt = 0; xt < 3; ++xt) {
                    bh[xt] = *(const short8*)(rowh + (xt * 16 + kx) * 32);
                    bl[xt] = *(const short8*)(rowl + (xt * 16 + kx) * 32);
                }
                #pragma unroll
                for (int mb = 0; mb < 4; ++mb)
                    #pragma unroll
                    for (int xt = 0; xt < 3; ++xt) {
                        acc[mb][xt] = __builtin_amdgcn_mfma_f32_16x16x32_bf16(ah[mb], bh[xt], acc[mb][xt], 0, 0, 0);
                        acc[mb][xt] = __builtin_amdgcn_mfma_f32_16x16x32_bf16(ah[mb], bl[xt], acc[mb][xt], 0, 0, 0);
                        acc[mb][xt] = __builtin_amdgcn_mfma_f32_16x16x32_bf16(al[mb], bh[xt], acc[mb][xt], 0, 0, 0);
                    }
            }
        }
    }
    float* ob = out + (((size_t)(n * 16 + t) * 48) + y) * (48 * 64);
    #pragma unroll
    for (int mb = 0; mb < 4; ++mb) {
        f32x4 bv = *(const f32x4*)(bias + mb * 16 + q * 4);
        #pragma unroll
        for (int xt = 0; xt < 3; ++xt) {
            f32x4 v = acc[mb][xt] + bv;
            *(f32x4*)(ob + (xt * 16 + c) * 64 + mb * 16 + q * 4) = v;
        }
    }
}

// -------- stats over conv2 out: [147456 s][64 c] -> sum/sumsq ---------------
__global__ void stats2k(const float* __restrict__ x, float* __restrict__ st) {
    int co = threadIdx.x & 63, sg = threadIdx.x >> 6;
    float s = 0.f, s2 = 0.f;
    int base = blockIdx.x * 1152 + sg;
    for (int i = 0; i < 288; ++i) {
        float v = x[(size_t)(base + i * 4) * 64 + co];
        s += v; s2 += v * v;
    }
    __shared__ float r[2][4][64];
    r[0][sg][co] = s; r[1][sg][co] = s2;
    __syncthreads();
    if (threadIdx.x < 64) {
        float a = 0.f, bsum = 0.f;
        #pragma unroll
        for (int g = 0; g < 4; ++g) { a += r[0][g][threadIdx.x]; bsum += r[1][g][threadIdx.x]; }
        atomicAdd(&st[threadIdx.x * 2], a);
        atomicAdd(&st[threadIdx.x * 2 + 1], bsum);
    }
}

// -------- bnpool2: conv2 out chan-last -> P3 [n][18][26][34][64] hi/lo ------
// Covers FULL padded range (writes zeros in pads; no memset needed for P3).
__global__ void bnpool2k(const float* __restrict__ cin, const float* __restrict__ st,
                         const float* __restrict__ gam, const float* __restrict__ bet,
                         unsigned short* __restrict__ phi, unsigned short* __restrict__ plo) {
    int i = blockIdx.x * 256 + threadIdx.x;    // 509184 = 4*18*26*34*8
    if (i >= 509184) return;
    int oc = i & 7; int xp = (i >> 3) % 34; int yp = (i / 272) % 26;
    int tp = (i / 7072) % 18; int n = i / 127296;
    union { unsigned short s[8]; uint4 v; } Uh, Ul;
    if (tp >= 1 && tp <= 16 && yp >= 1 && yp <= 24 && xp >= 1 && xp <= 24) {
        int t = tp - 1, yo = yp - 1, xo = xp - 1;
        const float* b0 = cin + ((((size_t)(n * 16 + t) * 48) + 2 * yo) * 48 + 2 * xo) * 64 + oc * 8;
        #pragma unroll
        for (int j = 0; j < 8; ++j) {
            int ch = oc * 8 + j;
            float mean = st[ch * 2] * (1.f / 147456.f);
            float var  = st[ch * 2 + 1] * (1.f / 147456.f) - mean * mean;
            var = var < 0.f ? 0.f : var;
            float sc = gam[ch] / sqrtf(var + 1e-5f);
            float sh = bet[ch] - mean * sc;
            float a  = b0[j] * sc + sh;
            float bb = b0[64 + j] * sc + sh;
            float c2 = b0[3072 + j] * sc + sh;
            float d  = b0[3136 + j] * sc + sh;
            float v = fmaxf(fmaxf(fmaxf(a, bb), fmaxf(c2, d)), 0.f);
            Uh.s[j] = f2bf(v);
            Ul.s[j] = f2bf(v - bf2f(Uh.s[j]));
        }
    } else {
        Uh.v = make_uint4(0, 0, 0, 0);
        Ul.v = make_uint4(0, 0, 0, 0);
    }
    size_t off = ((((size_t)n * 18 + tp) * 26 + yp) * 34 + xp) * 64 + oc * 8;
    *(uint4*)(phi + off) = Uh.v;
    *(uint4*)(plo + off) = Ul.v;
}

// -------- conv3: split-bf16 MFMA. in P3 [n][18][26][34][64] hi/lo ----------
// out: [n][16][24][24][128] fp32 chan-last. W3P: [2cg][3kt][3ky][3kx][2h][2kc][64co][32ci].
// Block: 4 waves, (cg,n,t,4-row strip); wave = 1 y-row, M=64, N=32 (x 24 valid).
__launch_bounds__(256, 3)
__global__ void conv3k(const unsigned short* __restrict__ phi, const unsigned short* __restrict__ plo,
                       const unsigned short* __restrict__ w3p, const float* __restrict__ bias,
                       float* __restrict__ out) {
    __shared__ unsigned short lds[24576];      // 48 KiB: one (kt,ky)-slab
    int b = blockIdx.x;                        // 768 = 2cg*4n*16t*6 strips
    int y0 = (b % 6) * 4; int t = (b / 6) % 16; int n = (b / 96) % 4; int cg = b / 384;
    int wv = threadIdx.x >> 6, lane = threadIdx.x & 63;
    int c = lane & 15, q = lane >> 4;
    int y = y0 + wv;

    f32x4 acc[4][2];
    #pragma unroll
    for (int i = 0; i < 4; ++i) { acc[i][0] = (f32x4)0.f; acc[i][1] = (f32x4)0.f; }

    const int laneoff = c * 64 + q * 8;        // B lane offset (x' * 64ci + q*8)
    const int aoff = c * 32 + q * 8;           // A lane offset within [co][ci32]
    const unsigned short* wsrc = w3p + (size_t)cg * 221184;

    for (int kt = 0; kt < 3; ++kt) {
        const unsigned short* ph_t = phi + (size_t)(n * 18 + t + kt) * (26 * 34 * 64);
        const unsigned short* pl_t = plo + (size_t)(n * 18 + t + kt) * (26 * 34 * 64);
        for (int ky = 0; ky < 3; ++ky) {
            const uint4* src = (const uint4*)(wsrc + (kt * 3 + ky) * 24576);
            uint4* dst = (uint4*)lds;
            __syncthreads();
            for (int i = threadIdx.x; i < 3072; i += 256) dst[i] = src[i];
            __syncthreads();
            const unsigned short* rowh = ph_t + (y + ky) * (34 * 64) + laneoff;
            const unsigned short* rowl = pl_t + (y + ky) * (34 * 64) + laneoff;
            #pragma unroll
            for (int kx = 0; kx < 3; ++kx) {
                #pragma unroll
                for (int kc = 0; kc < 2; ++kc) {
                    const unsigned short* wb = lds + kx * 8192 + kc * 2048 + aoff;
                    short8 ah[4], al[4], bh[2], bl[2];
                    #pragma unroll
                    for (int mb = 0; mb < 4; ++mb) {
                        ah[mb] = *(const short8*)(wb + mb * 512);
                        al[mb] = *(const short8*)(wb + 4096 + mb * 512);
                    }
                    #pragma unroll
                    for (int xt = 0; xt < 2; ++xt) {
                        bh[xt] = *(const short8*)(rowh + (xt * 16 + kx) * 64 + kc * 32);
                        bl[xt] = *(const short8*)(rowl + (xt * 16 + kx) * 64 + kc * 32);
                    }
                    #pragma unroll
                    for (int mb = 0; mb < 4; ++mb)
                        #pragma unroll
                        for (int xt = 0; xt < 2; ++xt) {
                            acc[mb][xt] = __builtin_amdgcn_mfma_f32_16x16x32_bf16(ah[mb], bh[xt], acc[mb][xt], 0, 0, 0);
                            acc[mb][xt] = __builtin_amdgcn_mfma_f32_16x16x32_bf16(ah[mb], bl[xt], acc[mb][xt], 0, 0, 0);
                            acc[mb][xt] = __builtin_amdgcn_mfma_f32_16x16x32_bf16(al[mb], bh[xt], acc[mb][xt], 0, 0, 0);
                        }
                }
            }
        }
    }
    float* ob = out + (((size_t)(n * 16 + t) * 24) + y) * (24 * 128) + cg * 64;
    #pragma unroll
    for (int mb = 0; mb < 4; ++mb) {
        f32x4 bv = *(const f32x4*)(bias + cg * 64 + mb * 16 + q * 4);
        f32x4 v0 = acc[mb][0] + bv;
        *(f32x4*)(ob + c * 128 + mb * 16 + q * 4) = v0;
        if (c < 8) {
            f32x4 v1 = acc[mb][1] + bv;
            *(f32x4*)(ob + (16 + c) * 128 + mb * 16 + q * 4) = v1;
        }
    }
}

// -------- stats over conv3 out: [36864 s][128 c] ----------------------------
__global__ void stats3k(const float* __restrict__ x, float* __restrict__ st) {
    int co = threadIdx.x & 127, sg = threadIdx.x >> 7;
    float s = 0.f, s2 = 0.f;
    int base = blockIdx.x * 576 + sg;
    for (int i = 0; i < 288; ++i) {
        float v = x[(size_t)(base + i * 2) * 128 + co];
        s += v; s2 += v * v;
    }
    __shared__ float r[2][2][128];
    r[0][sg][co] = s; r[1][sg][co] = s2;
    __syncthreads();
    if (threadIdx.x < 128) {
        float a = r[0][0][threadIdx.x] + r[0][1][threadIdx.x];
        float bsum = r[1][0][threadIdx.x] + r[1][1][threadIdx.x];
        atomicAdd(&st[threadIdx.x * 2], a);
        atomicAdd(&st[threadIdx.x * 2 + 1], bsum);
    }
}

// -------- BN + ReLU + avgpool 6x6 (chan-last in) -> enc ---------------------
__global__ void bnavgk(const float* __restrict__ x, const float* __restrict__ st,
                       const float* __restrict__ gam, const float* __restrict__ bet,
                       float* __restrict__ enc) {
    int i = blockIdx.x * 256 + threadIdx.x;    // 131072
    int c = i & 127; int xo = (i >> 7) & 3; int yo = (i >> 9) & 3;
    int t = (i >> 11) & 15; int n = i >> 15;
    float mean = st[c * 2] * (1.f / 36864.f);
    float var  = st[c * 2 + 1] * (1.f / 36864.f) - mean * mean;
    var = var < 0.f ? 0.f : var;
    float sc = gam[c] / sqrtf(var + 1e-5f);
    float sh = bet[c] - mean * sc;
    const float* base = x + ((((size_t)(n * 16 + t) * 24) + yo * 6) * 24 + xo * 6) * 128 + c;
    float s = 0.f;
    #pragma unroll
    for (int wy = 0; wy < 6; ++wy)
        #pragma unroll
        for (int wx = 0; wx < 6; ++wx)
            s += fmaxf(base[(wy * 24 + wx) * 128] * sc + sh, 0.f);
    enc[(size_t)n * 32768 + (size_t)c * 256 + t * 16 + yo * 4 + xo] = s * (1.f / 36.f);
}

// -------- weight prepack kernels -------------------------------------------
__global__ void prep2k(const float* __restrict__ c2w, unsigned short* __restrict__ w2p) {
    int i = blockIdx.x * 256 + threadIdx.x;    // 110592
    if (i >= 110592) return;
    int ci = i & 31; int co = (i >> 5) & 63; int h = (i >> 11) & 1;
    int o = (i >> 12) % 9; int kt = i / 36864;
    int ky = o / 3, kx = o % 3;
    float w = c2w[(((size_t)(co * 32 + ci) * 3 + kt) * 3 + ky) * 3 + kx];
    unsigned short hi = f2bf(w);
    w2p[i] = h ? f2bf(w - bf2f(hi)) : hi;
}
__global__ void prep3k(const float* __restrict__ c3w, unsigned short* __restrict__ w3p) {
    int i = blockIdx.x * 256 + threadIdx.x;    // 442368
    if (i >= 442368) return;
    int cil = i & 31; int cop = (i >> 5) & 63; int kc = (i >> 11) & 1; int h = (i >> 12) & 1;
    int kx = (i >> 13) % 3; int ky = (i / 24576) % 3; int kt = (i / 73728) % 3; int cg = i / 221184;
    int ci = kc * 32 + cil; int co = cg * 64 + cop;
    float w = c3w[(((size_t)(co * 64 + ci) * 3 + kt) * 3 + ky) * 3 + kx];
    unsigned short hi = f2bf(w);
    w3p[i] = h ? f2bf(w - bf2f(hi)) : hi;
}

// -------- proj: feat[n*7+l][d] = enc[l][n] . proj_w[d] + pb[d] --------------
__global__ void projk(const float* __restrict__ enc, const float* __restrict__ pw,
                      const float* __restrict__ pb, float* __restrict__ feat) {
    int d = blockIdx.x;
    float acc[28];
    #pragma unroll
    for (int e = 0; e < 28; ++e) acc[e] = 0.f;
    const float* wrow = pw + (size_t)d * 32768;
    for (int k = threadIdx.x; k < 32768; k += 256) {
        float wv = wrow[k];
        #pragma unroll
        for (int e = 0; e < 28; ++e) acc[e] += enc[(size_t)e * 32768 + k] * wv;
    }
    __shared__ float red[4 * 28];
    #pragma unroll
    for (int e = 0; e < 28; ++e) {
        float v = acc[e];
        #pragma unroll
        for (int o = 32; o > 0; o >>= 1) v += __shfl_down(v, o, 64);
        if ((threadIdx.x & 63) == 0) red[(threadIdx.x >> 6) * 28 + e] = v;
    }
    __syncthreads();
    if (threadIdx.x < 28) {
        int e = threadIdx.x;
        int l = e >> 2, n = e & 3;
        float s = red[e] + red[28 + e] + red[56 + e] + red[84 + e] + pb[d];
        feat[(size_t)(n * 7 + l) * 256 + d] = s;
    }
}

// -------- VQ: argmin_k (|c_k|^2 - 2 f.c_k), fp64, packed atomicMin ----------
__global__ void quantk(const float* __restrict__ feat, const float* __restrict__ cb,
                       unsigned long long* __restrict__ best) {
    __shared__ float fs[28 * 256];
    for (int i = threadIdx.x; i < 7168; i += 256) fs[i] = feat[i];
    __syncthreads();
    int k = blockIdx.x * 256 + threadIdx.x;
    const float* crow = cb + (size_t)k * 256;
    double dot[28];
    #pragma unroll
    for (int r = 0; r < 28; ++r) dot[r] = 0.0;
    double cn = 0.0;
    for (int d = 0; d < 256; ++d) {
        double c = (double)crow[d];
        cn += c * c;
        #pragma unroll
        for (int r = 0; r < 28; ++r) dot[r] += (double)fs[r * 256 + d] * c;
    }
    #pragma unroll
    for (int r = 0; r < 28; ++r) {
        float s = (float)(cn - 2.0 * dot[r]);
        unsigned int bits = __float_as_uint(s);
        unsigned int key = (bits & 0x80000000u) ? ~bits : (bits | 0x80000000u);
        unsigned long long p = ((unsigned long long)key << 32) | (unsigned int)k;
        #pragma unroll
        for (int o = 32; o > 0; o >>= 1) {
            unsigned long long qv = __shfl_down(p, o, 64);
            if (qv < p) p = qv;
        }
        if ((threadIdx.x & 63) == 0) atomicMin(&best[r], p);
    }
}

__global__ void gatherk(const unsigned long long* __restrict__ best,
                        const float* __restrict__ feat, const float* __restrict__ cb,
                        float* __restrict__ dout, float* __restrict__ quant,
                        float* __restrict__ acc) {
    int r = blockIdx.x;
    int d = threadIdx.x;
    int idx = (int)(best[r] & 0xFFFFFFFFull);
    float q = cb[(size_t)idx * 256 + d];
    quant[r * 256 + d] = q;
    dout[28 + r * 256 + d] = q;
    if (d == 0) dout[r] = (float)idx;
    float df = feat[r * 256 + d] - q;
    float v = df * df;
    #pragma unroll
    for (int o = 32; o > 0; o >>= 1) v += __shfl_down(v, o, 64);
    if ((d & 63) == 0) atomicAdd(&acc[0], v);
}

__global__ void gxk(const float* __restrict__ quant, const float* __restrict__ wih,
                    const float* __restrict__ bih, float* __restrict__ gx) {
    int o = blockIdx.x * 256 + threadIdx.x;
    int g = o % 768; int t = (o / 768) % 6; int n = o / (768 * 6);
    const float* q = quant + (size_t)(n * 7 + t) * 256;
    const float* w = wih + (size_t)g * 256;
    float s = bih[g];
    #pragma unroll 4
    for (int d = 0; d < 256; ++d) s += q[d] * w[d];
    gx[o] = s;
}

__global__ void gruk(const float* __restrict__ gx, const float* __restrict__ whh,
                     const float* __restrict__ bhh, float* __restrict__ h,
                     const float* __restrict__ feat, float* __restrict__ acc, int t) {
    int b = blockIdx.x;
    int d = threadIdx.x;
    __shared__ float hs[256];
    hs[d] = h[b * 256 + d];
    __syncthreads();
    float g0 = bhh[d], g1 = bhh[256 + d], g2 = bhh[512 + d];
    const float* w0 = whh + (size_t)d * 256;
    const float* w1 = whh + (size_t)(256 + d) * 256;
    const float* w2 = whh + (size_t)(512 + d) * 256;
    #pragma unroll 4
    for (int k = 0; k < 256; ++k) {
        float hv = hs[k];
        g0 += w0[k] * hv; g1 += w1[k] * hv; g2 += w2[k] * hv;
    }
    const float* gxr = gx + (size_t)(b * 6 + t) * 768;
    float xr = gxr[d], xz = gxr[256 + d], xn = gxr[512 + d];
    float rr = 1.f / (1.f + expf(-(xr + g0)));
    float zz = 1.f / (1.f + expf(-(xz + g1)));
    float nn = tanhf(xn + rr * g2);
    float h2 = (1.f - zz) * nn + zz * hs[d];
    h[b * 256 + d] = h2;
    float df = h2 - feat[(size_t)(b * 7 + t + 1) * 256 + d];
    float v = df * df;
    #pragma unroll
    for (int o = 32; o > 0; o >>= 1) v += __shfl_down(v, o, 64);
    if ((d & 63) == 0) atomicAdd(&acc[1], v);
}

__global__ void fink(const float* __restrict__ acc, float* __restrict__ dout) {
    float comm = acc[0] / 7168.f;
    float ctx  = acc[1] / 6144.f;
    dout[7196] = comm;
    dout[7197] = comm;
    dout[7198] = ctx;
    dout[7199] = comm + 0.25f * comm + 0.1f * ctx;
}

// ---------------------------------------------------------------------------
extern "C" void kernel_launch(void* const* d_in, const int* in_sizes, int n_in,
                              void* d_out, int out_size, void* d_ws, size_t ws_size,
                              hipStream_t stream) {
    (void)in_sizes; (void)n_in; (void)out_size; (void)ws_size;
    const float* x    = (const float*)d_in[0];
    const float* c1w  = (const float*)d_in[1];
    const float* c1b  = (const float*)d_in[2];
    const float* bn1g = (const float*)d_in[3];
    const float* bn1b = (const float*)d_in[4];
    const float* c2w  = (const float*)d_in[5];
    const float* c2b  = (const float*)d_in[6];
    const float* bn2g = (const float*)d_in[7];
    const float* bn2b = (const float*)d_in[8];
    const float* c3w  = (const float*)d_in[9];
    const float* c3b  = (const float*)d_in[10];
    const float* bn3g = (const float*)d_in[11];
    const float* bn3b = (const float*)d_in[12];
    const float* pw   = (const float*)d_in[13];
    const float* pb   = (const float*)d_in[14];
    const float* cb   = (const float*)d_in[15];
    const float* wih  = (const float*)d_in[16];
    const float* whh  = (const float*)d_in[17];
    const float* bih  = (const float*)d_in[18];
    const float* bhh  = (const float*)d_in[19];
    float* out = (float*)d_out;

    // ---- workspace layout (bytes) ----
    char* w = (char*)d_ws;
    float* A  = (float*)w;                         w += 75497472;   // conv outs (chan-first c1 / chan-last c2,c3)
    char*  SH = w;                                 w += 16293888;   // P1 fp32 (8.47MB) aliased with P3 hi/lo
    float* P1 = (float*)SH;
    unsigned short* P3h = (unsigned short*)SH;
    unsigned short* P3l = (unsigned short*)(SH + 8146944);
    unsigned short* P2h = (unsigned short*)w;      w += 11980800;
    unsigned short* P2l = (unsigned short*)w;      w += 11980800;
    unsigned short* W2P = (unsigned short*)w;      w += 221184;
    unsigned short* W3P = (unsigned short*)w;      w += 884736;
    float* enc   = (float*)w;                      w += 3670016;
    float* feat  = (float*)w;                      w += 28672;
    float* quant = (float*)w;                      w += 28672;
    float* gx    = (float*)w;                      w += 73728;
    // zero-region: statsA (21*256 f) + acc (4 f) + h (1024 f)
    float* statsA = (float*)w;                     w += 21504;
    float* acc    = (float*)w;                     w += 16;
    float* h      = (float*)w;                     w += 4096;
    unsigned long long* best = (unsigned long long*)w;  w += 224;

    // ---- one-time (per launch) init ----
    hipMemsetAsync(P2h, 0, 11980800 * 2, stream);                  // P2 hi+lo pads
    hipMemsetAsync(statsA, 0, 21504 + 16 + 4096, stream);          // stats + acc + h
    hipMemsetAsync(best, 0xFF, 224, stream);
    prep2k<<<432, 256, 0, stream>>>(c2w, W2P);
    prep3k<<<1728, 256, 0, stream>>>(c3w, W3P);

    for (int l = 0; l < 7; ++l) {
        float* st1 = statsA + (l * 3 + 0) * 256;
        float* st2 = statsA + (l * 3 + 1) * 256;
        float* st3 = statsA + (l * 3 + 2) * 256;
        pad_clip_k<<<8269, 256, 0, stream>>>(x, P1, l * 8);
        convk<3, 32, 96, 96, 100, 1, 256><<<2048, 256, 0, stream>>>(P1, c1w, c1b, A, st1);
        bnpool1k<<<3072, 256, 0, stream>>>(A, st1, bn1g, bn1b, P2h, P2l);
        conv2k<<<768, 256, 0, stream>>>(P2h, P2l, W2P, c2b, A);
        stats2k<<<128, 256, 0, stream>>>(A, st2);
        bnpool2k<<<1989, 256, 0, stream>>>(A, st2, bn2g, bn2b, P3h, P3l);
        conv3k<<<768, 256, 0, stream>>>(P3h, P3l, W3P, c3b, A);
        stats3k<<<64, 256, 0, stream>>>(A, st3);
        bnavgk<<<512, 256, 0, stream>>>(A, st3, bn3g, bn3b, enc + (size_t)l * 131072);
    }

    projk<<<256, 256, 0, stream>>>(enc, pw, pb, feat);
    quantk<<<32, 256, 0, stream>>>(feat, cb, best);
    gatherk<<<28, 256, 0, stream>>>(best, feat, cb, out, quant, acc);
    gxk<<<72, 256, 0, stream>>>(quant, wih, bih, gx);
    for (int t = 0; t < 6; ++t)
        gruk<<<4, 256, 0, stream>>>(gx, whh, bhh, h, feat, acc, t);
    fink<<<1, 1, 0, stream>>>(acc, out);
}